// Round 2
// baseline (2540.840 us; speedup 1.0000x reference)
//
#include <hip/hip_runtime.h>

// AdEx Euler integration, fp32 port of the jax/numpy reference.
// T=40000 sequential steps; N=1024 neurons -> 16 producer waves on 16 CUs.
//
// MODEL: lone in-order wave dispatches ~1 instr / 5.6 cyc -> dispatch-slot
// bound. R13->R14 removed 1 slot/step and gained exactly 95us (= 40000 x
// 5.6cyc) -> model holds. R15 (reg-array AD prefetch + pk_fma) was a WASH
// (1632->1624): VGPR_Count stayed 132, i.e. the 128-VGPR prefetch arrays
// were never kept resident -- compiler sank the loads to use sites and the
// vmcnt waits ate the savings. Lesson: slot cuts must be UNSINKABLE.
//
// R16 (this): remove the register-array degree of freedom entirely.
//   - AD staged through LDS: ONE global_load_lds (64 lanes x 4B = 256B =
//     one 32-step buffer of {Ar2,delta} pairs), issued 1 buffer ahead,
//     vmcnt(0) once per buffer. Per pair: one lane-uniform ds_read_b128
//     (same-address broadcast, conflict-free) -> both pk addend pairs.
//     ~0.56 slots/step, zero VGPR pressure, nothing to sink.
//   - pk_fma #2 in-place ("+v"(VW), src1 hi-broadcast; HW reads before
//     write): VW pair stays the architectural state, no P2->VW copy.
//   - pre-state staged as 2x ds_write_b64 (bytes 0-8 / 8-16 of the same
//     float4 slot; consumer unchanged). Write data IS the live VW pair ->
//     no quad-assembly movs. Stride-16 b64 = 2-way bank alias = free.
//   - spike handling branched out: v_cmp on old V + uniform
//     if(__ballot(sp)) skip. Spiking steps are rare (~1-3%); common path
//     drops the +b add and both cndmasks. Fixup ops value-identical ->
//     trajectory bit-exact (absmax must stay EXACTLY 4.882812e-04).
// Ideal common path ~9.5 slots/step -> predict ~1100-1250 us kernel.

typedef float v2f __attribute__((ext_vector_type(2)));

__device__ __forceinline__ float exp2_raw(float u) {
    float r;
    asm("v_exp_f32 %0, %1" : "=v"(r) : "v"(u));   // r = 2^u, ~1 ulp
    return r;
}

// s_waitcnt lgkmcnt(0) (vmcnt max, expcnt max, lgkmcnt 0).
#define LGKM0() __builtin_amdgcn_s_waitcnt(0xC07F)
// s_waitcnt vmcnt(0)  (lgkmcnt max 0x3F<<8, expcnt max 7<<4, vmcnt 0).
#define VM0()   __builtin_amdgcn_s_waitcnt(0x3F70)

// ---------------------------------------------------------------------------
// Prep: AD[k] = {Ar2_k, delta} for k in [0, T+32). Bit-identical constant
// folding to the producer's original in-loop computation (same f64
// expressions, rounded once to f32; same fmaf on the same I value).
// ---------------------------------------------------------------------------
__global__ void __launch_bounds__(256) adex_prep_kernel(
    const float* __restrict__ I_ext,
    const float* __restrict__ p_V_rest,
    const float* __restrict__ p_R,
    const float* __restrict__ p_tau,
    const float* __restrict__ p_tau_w,
    const float* __restrict__ p_a,
    float2* __restrict__ AD, int T)
{
#pragma clang fp contract(off)
    int k = blockIdx.x * 256 + threadIdx.x;
    if (k >= T + 32) return;

    const float V_rest = *p_V_rest;
    const float R      = *p_R;
    const float tau    = *p_tau;
    const float tau_w  = *p_tau_w;
    const float a      = *p_a;
    const float dt     = 5e-5f;

    const double dcv = (double)dt / (double)tau;
    const double dcw = (double)dt / (double)tau_w;

    const float cRI   = (float)(dcv * (double)R);
    const float cVr2  = (float)(dcv * (double)V_rest);
    const float delta = (float)(-(double)a * dcw * (double)V_rest);

    int ki = (k <= T + 4) ? k : (T + 4);      // tail entries never consumed
    AD[k] = make_float2(fmaf(cRI, I_ext[ki], cVr2), delta);
}

// ---------------------------------------------------------------------------
// Main producer/consumer kernel.
// ---------------------------------------------------------------------------
__global__ void __launch_bounds__(128, 1) adex_pc_kernel(
    const float* __restrict__ V0,
    const float* __restrict__ w0,
    const float* __restrict__ p_V_reset,
    const float* __restrict__ p_V_T,
    const float* __restrict__ p_V_thres,
    const float* __restrict__ p_delta_T,
    const float* __restrict__ p_R,
    const float* __restrict__ p_tau,
    const float* __restrict__ p_tau_w,
    const float* __restrict__ p_a,
    const float* __restrict__ p_b,
    const float* __restrict__ ADf,       // workspace: {Ar2,delta} pairs as floats
    float* __restrict__ out,
    int T, int N)
{
#pragma clang fp contract(off)
    // Ring of 4 buffers x 16 step-pairs x 64 lanes x float4 = 64 KiB.
    __shared__ float4 stage[4][16][64];
    // AD staging: 2 slots x 16 quads (= 32 {Ar2,delta} pairs = 256 B each).
    __shared__ float4 ad_stage[2][16];
    __shared__ int    flags[2];          // [0]=produced bufs, [1]=consumed

    const int tid   = threadIdx.x;
    const int l     = tid & 63;
    const int wave  = tid >> 6;
    const int nbase = blockIdx.x * 64;   // N % 64 == 0

    volatile int* vflags = (volatile int*)flags;
    if (tid < 2) flags[tid] = 0;
    __syncthreads();                     // once, at kernel start only

    const int NB = T >> 5;               // 32-step buffers (T % 64 == 0)

    if (wave == 0) {
        // ---------------- producer: the serial recurrence ----------------
        const float V_reset = *p_V_reset;
        const float V_T     = *p_V_T;
        const float V_thres = *p_V_thres;
        const float delta_T = *p_delta_T;
        const float R       = *p_R;
        const float tau     = *p_tau;
        const float tau_w   = *p_tau_w;
        const float a       = *p_a;
        const float b       = *p_b;
        const float dt      = 5e-5f;

        // Constants folded in f64, rounded once to f32 (bit-neutral class).
        const double dT  = (double)delta_T;
        const double dcv = (double)dt / (double)tau;
        const double dcw = (double)dt / (double)tau_w;
        const double l2e = 1.4426950408889634;

        const float c_exp = (float)(l2e / dT);
        const float c2    = (float)(log2(dT * dcv) - (double)V_T * (l2e / dT));
        const float alpha = (float)(1.0 - dcv);
        const float ncRv  = (float)(-dcv * (double)R);
        const float beta  = (float)(1.0 - dcw);
        const float gamma = (float)((double)a * dcw);

        // Packed coefficient pairs for v_pk_fma_f32.
        v2f cAG; cAG.x = alpha; cAG.y = gamma;
        v2f cNB; cNB.x = ncRv;  cNB.y = beta;

        // Packed state {V, w}.
        v2f VW;
        VW.x = V0[nbase + l];
        VW.y = w0[nbase + l];

        // One step. All fp ops value-identical to the verified R14 math:
        //   P1.lo = fma(alpha,V,Ar2)    P1.hi = fma(gamma,V,delta)
        //   VW.lo = fma(ncRv,w,P1.lo)   VW.hi = fma(beta,w,P1.hi)   (in-place)
        //   VW.x += 2^fma(V,c_exp,c2);  rare spike fixup via cndmask.
#define ADEX_MATH(ADP)                                                    \
        {                                                                 \
            float u  = fmaf(VW.x, c_exp, c2);                             \
            bool  sp = VW.x > V_thres;                                    \
            float ex = exp2_raw(u);                                       \
            v2f P1;                                                       \
            asm("v_pk_fma_f32 %0, %1, %2, %3 op_sel:[0,0,0] op_sel_hi:[1,0,1]" \
                : "=v"(P1) : "v"(cAG), "v"(VW), "v"(ADP));                \
            asm("v_pk_fma_f32 %0, %1, %0, %2 op_sel:[0,1,0] op_sel_hi:[1,1,1]" \
                : "+v"(VW) : "v"(cNB), "v"(P1));                          \
            VW.x += ex;                                                   \
            if (__builtin_expect(__ballot(sp) != 0, 0)) {                 \
                VW.x = sp ? V_reset : VW.x;                               \
                VW.y = sp ? VW.y + b : VW.y;                              \
            }                                                             \
        }

        // Prologue: stage AD buffer 0 into LDS slot 0.
        {
            __builtin_amdgcn_global_load_lds(
                (const __attribute__((address_space(1))) unsigned int*)(ADf + l),
                (__attribute__((address_space(3))) unsigned int*)&ad_stage[0][0],
                4, 0, 0);
        }

        for (int pi = 0; pi < NB; ++pi) {
            // Back-pressure every 2nd buffer: ring is 4 deep; producing pi
            // needs consumed >= pi-3; checking >= pi-2 covers pi and pi+1.
            if (!(pi & 1)) {
                while (vflags[1] < pi - 2) __builtin_amdgcn_s_sleep(2);
            }
            asm volatile("" ::: "memory");

            VM0();                        // AD slot (pi&1) resident

            // Issue next buffer's AD stage (tail-clamped; never read).
            {
                int nb = pi + 1 < NB ? pi + 1 : NB - 1;
                __builtin_amdgcn_global_load_lds(
                    (const __attribute__((address_space(1))) unsigned int*)(ADf + nb * 64 + l),
                    (__attribute__((address_space(3))) unsigned int*)&ad_stage[(pi + 1) & 1][0],
                    4, 0, 0);
            }

            const float4* adb = &ad_stage[pi & 1][0];
            float4*       sb  = &stage[pi & 3][0][l];

#pragma unroll
            for (int s = 0; s < 16; ++s) {
                float4 q = adb[s];                         // lane-uniform b128
                v2f ad0; ad0.x = q.x; ad0.y = q.y;
                v2f ad1; ad1.x = q.z; ad1.y = q.w;
                ((v2f*)(sb + s * 64))[0] = VW;             // pre-state, step 2s
                ADEX_MATH(ad0);
                ((v2f*)(sb + s * 64))[1] = VW;             // pre-state, step 2s+1
                ADEX_MATH(ad1);
            }

            LGKM0();
            asm volatile("" ::: "memory");
            vflags[0] = pi + 1;
        }
#undef ADEX_MATH
    } else {
        // ---------------- consumer: drain LDS -> global ----------------
        float* outV = out + nbase + l;
        float* outW = out + (size_t)T * N + nbase + l;

        for (int ci = 0; ci < NB; ++ci) {
            while (vflags[0] < ci + 1) __builtin_amdgcn_s_sleep(2);
            asm volatile("" ::: "memory");
            const float4* cb = &stage[ci & 3][0][l];
#pragma unroll
            for (int s = 0; s < 16; ++s) {
                float4 q = cb[s * 64];
                outV[0] = q.x;          // step 2s
                outW[0] = q.y;
                outV[N] = q.z;          // step 2s+1
                outW[N] = q.w;
                outV += 2 * N;
                outW += 2 * N;
            }
            // LDS reads retired (store data deps forced waits); slot free.
            asm volatile("" ::: "memory");
            vflags[1] = ci + 1;
        }
    }
}

// Fallback: R11-style single-wave kernel for shapes that don't meet the
// producer/consumer preconditions (N%64, T%64, workspace size).
__global__ void __launch_bounds__(64, 1) adex_fallback_kernel(
    const float* __restrict__ I_ext,
    const float* __restrict__ V0,
    const float* __restrict__ w0,
    const float* __restrict__ p_V_rest,
    const float* __restrict__ p_V_reset,
    const float* __restrict__ p_V_T,
    const float* __restrict__ p_V_thres,
    const float* __restrict__ p_delta_T,
    const float* __restrict__ p_R,
    const float* __restrict__ p_tau,
    const float* __restrict__ p_tau_w,
    const float* __restrict__ p_a,
    const float* __restrict__ p_b,
    float* __restrict__ out,
    int T, int N)
{
#pragma clang fp contract(off)
    const int l     = threadIdx.x;
    const int nbase = blockIdx.x * 64;
    int n = nbase + l;
    if (n >= N) n = N - 1;

    const float V_rest  = *p_V_rest;
    const float V_reset = *p_V_reset;
    const float V_T     = *p_V_T;
    const float V_thres = *p_V_thres;
    const float delta_T = *p_delta_T;
    const float R       = *p_R;
    const float tau     = *p_tau;
    const float tau_w   = *p_tau_w;
    const float a       = *p_a;
    const float b       = *p_b;
    const float dt      = 5e-5f;

    const double dT  = (double)delta_T;
    const double dcv = (double)dt / (double)tau;
    const double dcw = (double)dt / (double)tau_w;
    const double l2e = 1.4426950408889634;

    const float c_exp = (float)(l2e / dT);
    const float c2    = (float)(log2(dT * dcv) - (double)V_T * (l2e / dT));
    const float alpha = (float)(1.0 - dcv);
    const float ncRv  = (float)(-dcv * (double)R);
    const float beta  = (float)(1.0 - dcw);
    const float gamma = (float)((double)a * dcw);
    const float delta = (float)(-(double)a * dcw * (double)V_rest);
    const float cRI   = (float)(dcv * (double)R);
    const float cVr2  = (float)(dcv * (double)V_rest);

    float V = V0[n];
    float w = w0[n];

    float* outVb = out + nbase;
    float* outWb = out + (size_t)T * N + nbase;

#define ADEX_STEP(Ar2_k)                                            \
    {                                                               \
        outVb[l] = V;                                               \
        outWb[l] = w;                                               \
        outVb += N;                                                 \
        outWb += N;                                                 \
        float ex3 = exp2_raw(fmaf(V, c_exp, c2));                   \
        float m1  = fmaf(alpha, V, (Ar2_k));                        \
        float m2  = fmaf(ncRv, w, m1);                              \
        float Vn  = m2 + ex3;                                       \
        float t2  = fmaf(gamma, V, delta);                          \
        float wn  = fmaf(beta, w, t2);                              \
        bool  spike = V > V_thres;                                  \
        float wns = wn + b;                                         \
        Vn = spike ? V_reset : Vn;                                  \
        wn = spike ? wns : wn;                                      \
        V = Vn;                                                     \
        w = wn;                                                     \
    }

    float A[16], B[16];
#pragma unroll
    for (int j = 0; j < 16; ++j) A[j] = fmaf(cRI, I_ext[j], cVr2);

    for (int kb = 0; kb < T; kb += 32) {
#pragma unroll
        for (int j = 0; j < 16; ++j)
            B[j] = fmaf(cRI, I_ext[kb + 16 + j], cVr2);
#pragma unroll
        for (int j = 0; j < 16; ++j) ADEX_STEP(A[j]);
        {
            int pb = kb + 32;
            if (pb > T - 11) pb = T - 11;
#pragma unroll
            for (int j = 0; j < 16; ++j)
                A[j] = fmaf(cRI, I_ext[pb + j], cVr2);
        }
#pragma unroll
        for (int j = 0; j < 16; ++j) ADEX_STEP(B[j]);
    }
#undef ADEX_STEP
}

extern "C" void kernel_launch(void* const* d_in, const int* in_sizes, int n_in,
                              void* d_out, int out_size, void* d_ws, size_t ws_size,
                              hipStream_t stream) {
    const float* I_ext = (const float*)d_in[0];
    const float* V0    = (const float*)d_in[1];
    const float* w0    = (const float*)d_in[2];

    const int N = in_sizes[1];          // 1024 (multiple of 64)
    const int T = out_size / (2 * N);   // 40000 (multiple of 64)

    const size_t ws_need = (size_t)(T + 32) * sizeof(float2);

    if ((N % 64 == 0) && (T % 64 == 0) && d_ws != nullptr && ws_size >= ws_need) {
        adex_prep_kernel<<<(T + 32 + 255) / 256, 256, 0, stream>>>(
            I_ext,
            (const float*)d_in[3],      // V_rest
            (const float*)d_in[8],      // R
            (const float*)d_in[9],      // tau
            (const float*)d_in[10],     // tau_w
            (const float*)d_in[11],     // a
            (float2*)d_ws, T);
        adex_pc_kernel<<<N / 64, 128, 0, stream>>>(
            V0, w0,
            (const float*)d_in[4],      // V_reset
            (const float*)d_in[5],      // V_T
            (const float*)d_in[6],      // V_thres
            (const float*)d_in[7],      // delta_T
            (const float*)d_in[8],      // R
            (const float*)d_in[9],      // tau
            (const float*)d_in[10],     // tau_w
            (const float*)d_in[11],     // a
            (const float*)d_in[12],     // b
            (const float*)d_ws,
            (float*)d_out, T, N);
    } else {
        adex_fallback_kernel<<<(N + 63) / 64, 64, 0, stream>>>(
            I_ext, V0, w0,
            (const float*)d_in[3], (const float*)d_in[4], (const float*)d_in[5],
            (const float*)d_in[6], (const float*)d_in[7], (const float*)d_in[8],
            (const float*)d_in[9], (const float*)d_in[10], (const float*)d_in[11],
            (const float*)d_in[12], (float*)d_out, T, N);
    }
}

// Round 3
// 1619.735 us; speedup vs baseline: 1.5687x; 1.5687x over previous
//
#include <hip/hip_runtime.h>

// AdEx Euler integration, fp32 port of the jax/numpy reference.
// T=40000 sequential steps; N=1024 neurons -> 16 producer waves on 16 CUs.
//
// MODEL: lone in-order wave dispatches ~1 instr / 5.6 cyc -> dispatch-slot
// bound. R13->R14 (-1 slot/step) gained exactly 95us -> model holds.
// R15: reg-array AD prefetch was SUNK by compiler (VGPR stayed 132) -> wash.
// R16: AD via LDS = per-pair lgkmcnt serialization + 8-way-conflicted
//      ds_write_b64 @16B stride (SQ_LDS_BANK_CONFLICT 0 -> 2.56M) -> 2264us.
//
// R17 (this): AD in registers via UNSINKABLE volatile-asm loads.
//   - 32x volatile "global_load_dwordx2" per 32-step buffer into an
//     explicit A/B register double-buffer (128 VGPR). Volatile asm can't be
//     sunk/rematerialized. Wait = s_waitcnt vmcnt(32) (+sched_barrier(0),
//     rule-#18 guard) at buffer start: newest 32 loads (next buffer) stay
//     in flight, current set guaranteed resident -> zero stall. AD pairs
//     feed v_pk_fma src2 directly as aligned VGPR pairs, no movs, no fma.
//   - staging = ONE ds_write_b64 per step, layout [buf][step][lane] float2:
//     8B lane stride = contiguous 512B/wave = conflict-free. Write data IS
//     the live VW pair (no quad-assembly movs -- what ate R15's pk gain).
//   - math: validated pk_fma pair (bit-exact R15/R16) + unconditional
//     spike selects. absmax must stay EXACTLY 4.882812e-04.
// Producer ~11.2 slots/step ~= 63 cyc vs R14's measured 98.
// Predict kernel 1100-1350us; VGPR ~170-210; bank conflicts ~0.

typedef float v2f __attribute__((ext_vector_type(2)));
typedef unsigned long long u64;

__device__ __forceinline__ float exp2_raw(float u) {
    float r;
    asm("v_exp_f32 %0, %1" : "=v"(r) : "v"(u));   // r = 2^u, ~1 ulp
    return r;
}

// s_waitcnt lgkmcnt(0) (vmcnt max, expcnt max, lgkmcnt 0).
#define LGKM0() __builtin_amdgcn_s_waitcnt(0xC07F)

// ---------------------------------------------------------------------------
// Prep: AD[k] = {Ar2_k, delta} for k in [0, T+32). Bit-identical constant
// folding to the producer's original in-loop computation (same f64
// expressions, rounded once to f32; same fmaf on the same I value).
// ---------------------------------------------------------------------------
__global__ void __launch_bounds__(256) adex_prep_kernel(
    const float* __restrict__ I_ext,
    const float* __restrict__ p_V_rest,
    const float* __restrict__ p_R,
    const float* __restrict__ p_tau,
    const float* __restrict__ p_tau_w,
    const float* __restrict__ p_a,
    float2* __restrict__ AD, int T)
{
#pragma clang fp contract(off)
    int k = blockIdx.x * 256 + threadIdx.x;
    if (k >= T + 32) return;

    const float V_rest = *p_V_rest;
    const float R      = *p_R;
    const float tau    = *p_tau;
    const float tau_w  = *p_tau_w;
    const float a      = *p_a;
    const float dt     = 5e-5f;

    const double dcv = (double)dt / (double)tau;
    const double dcw = (double)dt / (double)tau_w;

    const float cRI   = (float)(dcv * (double)R);
    const float cVr2  = (float)(dcv * (double)V_rest);
    const float delta = (float)(-(double)a * dcw * (double)V_rest);

    int ki = (k <= T + 4) ? k : (T + 4);      // tail entries never consumed
    AD[k] = make_float2(fmaf(cRI, I_ext[ki], cVr2), delta);
}

// ---------------------------------------------------------------------------
// Main producer/consumer kernel.
// ---------------------------------------------------------------------------
__global__ void __launch_bounds__(128, 1) adex_pc_kernel(
    const float* __restrict__ V0,
    const float* __restrict__ w0,
    const float* __restrict__ p_V_reset,
    const float* __restrict__ p_V_T,
    const float* __restrict__ p_V_thres,
    const float* __restrict__ p_delta_T,
    const float* __restrict__ p_R,
    const float* __restrict__ p_tau,
    const float* __restrict__ p_tau_w,
    const float* __restrict__ p_a,
    const float* __restrict__ p_b,
    const float* __restrict__ ADf,       // workspace: {Ar2,delta} pairs
    float* __restrict__ out,
    int T, int N)
{
#pragma clang fp contract(off)
    // Ring of 4 buffers x 32 steps x 64 lanes x float2 = 64 KiB.
    // [buf][step][lane]: lane stride 8B -> ds b64 ops fully contiguous.
    __shared__ v2f stage[4][32][64];
    __shared__ int flags[2];             // [0]=produced bufs, [1]=consumed

    const int tid   = threadIdx.x;
    const int l     = tid & 63;
    const int wave  = tid >> 6;
    const int nbase = blockIdx.x * 64;   // N % 64 == 0

    volatile int* vflags = (volatile int*)flags;
    if (tid < 2) flags[tid] = 0;
    __syncthreads();                     // once, at kernel start only

    const int NB = T >> 5;               // 32-step buffers (T % 64 == 0 -> NB even)

    if (wave == 0) {
        // ---------------- producer: the serial recurrence ----------------
        const float V_reset = *p_V_reset;
        const float V_T     = *p_V_T;
        const float V_thres = *p_V_thres;
        const float delta_T = *p_delta_T;
        const float R       = *p_R;
        const float tau     = *p_tau;
        const float tau_w   = *p_tau_w;
        const float a       = *p_a;
        const float b       = *p_b;
        const float dt      = 5e-5f;

        // Constants folded in f64, rounded once to f32 (bit-neutral class).
        const double dT  = (double)delta_T;
        const double dcv = (double)dt / (double)tau;
        const double dcw = (double)dt / (double)tau_w;
        const double l2e = 1.4426950408889634;

        const float c_exp = (float)(l2e / dT);
        const float c2    = (float)(log2(dT * dcv) - (double)V_T * (l2e / dT));
        const float alpha = (float)(1.0 - dcv);
        const float ncRv  = (float)(-dcv * (double)R);
        const float beta  = (float)(1.0 - dcw);
        const float gamma = (float)((double)a * dcw);

        // Packed coefficient pairs for v_pk_fma_f32.
        v2f cAG; cAG.x = alpha; cAG.y = gamma;
        v2f cNB; cNB.x = ncRv;  cNB.y = beta;

        // Packed state {V, w}.
        v2f VW;
        VW.x = V0[nbase + l];
        VW.y = w0[nbase + l];

        // AD double-buffer register sets. Constant-indexed in fully
        // unrolled loops -> SROA to 64 discrete u64 (128 VGPR), defined
        // only by volatile asm loads -> unsinkable, guaranteed resident.
        u64 A[32], B[32];
        const unsigned long long adbase = (unsigned long long)ADf;

        // Issue one buffer's 32 {Ar2,delta} pairs. voff uniform; offsets
        // are compile-time immediates.
#define LDSET(ARR, VOFF)                                                  \
        {                                                                 \
            unsigned _vo = (VOFF);                                        \
            _Pragma("unroll")                                             \
            for (int j = 0; j < 32; ++j)                                  \
                asm volatile("global_load_dwordx2 %0, %1, %2 offset:%3"   \
                             : "=v"(ARR[j])                               \
                             : "v"(_vo), "s"(adbase), "n"(j * 8));        \
        }

        // One step. All fp ops value-identical to the verified R14 math:
        //   P1.lo = fma(alpha,V,Ar2)    P1.hi = fma(gamma,V,delta)
        //   VW.lo = fma(ncRv,w,P1.lo)   VW.hi = fma(beta,w,P1.hi)  (in-place)
        //   VW.x += 2^fma(V,c_exp,c2);  unconditional spike selects.
        // Pre-step state is staged FIRST (solution[k] = state before step k).

        // One 32-step buffer from register set ARR. vmcnt(32): the newest
        // 32 loads (next buffer's set) stay in flight; everything older
        // (ARR) is resident. sched_barrier stops reg-only asm from being
        // hoisted above the wait (rule #18).
#define PRODUCE(ARR)                                                      \
        {                                                                 \
            asm volatile("s_waitcnt vmcnt(32)");                          \
            __builtin_amdgcn_sched_barrier(0);                            \
            v2f* sb = &stage[pi & 3][0][l];                               \
            _Pragma("unroll")                                             \
            for (int s = 0; s < 32; ++s) {                                \
                sb[s * 64] = VW;                                          \
                float u  = fmaf(VW.x, c_exp, c2);                         \
                bool  sp = VW.x > V_thres;                                \
                float ex = exp2_raw(u);                                   \
                v2f P1;                                                   \
                asm("v_pk_fma_f32 %0, %1, %2, %3 op_sel:[0,0,0] op_sel_hi:[1,0,1]" \
                    : "=v"(P1) : "v"(cAG), "v"(VW), "v"(ARR[s]));         \
                asm("v_pk_fma_f32 %0, %1, %0, %2 op_sel:[0,1,0] op_sel_hi:[1,1,1]" \
                    : "+v"(VW) : "v"(cNB), "v"(P1));                      \
                VW.x += ex;                                               \
                float wns = VW.y + b;                                     \
                VW.x = sp ? V_reset : VW.x;                               \
                VW.y = sp ? wns : VW.y;                                   \
            }                                                             \
            LGKM0();                                                      \
            asm volatile("" ::: "memory");                                \
            ++pi;                                                         \
            vflags[0] = pi;                                               \
        }

        // Prologue: buffer 0 into set A.
        LDSET(A, 0u);

        int pi = 0;
        unsigned voff = 0;
        while (pi < NB) {
            // Back-pressure every 2nd buffer: ring 4 deep; producing pi
            // needs consumed >= pi-3; checking >= pi-2 covers pi and pi+1.
            while (vflags[1] < pi - 2) __builtin_amdgcn_s_sleep(2);
            asm volatile("" ::: "memory");

            voff += 256;
            LDSET(B, voff);        // buffer pi+1
            PRODUCE(A);

            voff += 256;
            LDSET(A, voff);        // buffer pi+2 (last issue reads the
                                   // (T+32)-entry AD tail; never consumed)
            PRODUCE(B);
        }
#undef PRODUCE
#undef LDSET
    } else {
        // ---------------- consumer: drain LDS -> global ----------------
        float* __restrict__ outw = out + (size_t)T * N;
        unsigned idx = (unsigned)(nbase + l);      // += N per step

        for (int ci = 0; ci < NB; ++ci) {
            while (vflags[0] < ci + 1) __builtin_amdgcn_s_sleep(2);
            asm volatile("" ::: "memory");
            const v2f* cb = &stage[ci & 3][0][l];
#pragma unroll
            for (int s = 0; s < 32; ++s) {
                v2f q = cb[s * 64];
                out[idx]  = q.x;
                outw[idx] = q.y;
                idx += (unsigned)N;
            }
            // LDS reads retired (store data deps forced waits); slot free.
            asm volatile("" ::: "memory");
            vflags[1] = ci + 1;
        }
    }
}

// Fallback: R11-style single-wave kernel for shapes that don't meet the
// producer/consumer preconditions (N%64, T%64, workspace size).
__global__ void __launch_bounds__(64, 1) adex_fallback_kernel(
    const float* __restrict__ I_ext,
    const float* __restrict__ V0,
    const float* __restrict__ w0,
    const float* __restrict__ p_V_rest,
    const float* __restrict__ p_V_reset,
    const float* __restrict__ p_V_T,
    const float* __restrict__ p_V_thres,
    const float* __restrict__ p_delta_T,
    const float* __restrict__ p_R,
    const float* __restrict__ p_tau,
    const float* __restrict__ p_tau_w,
    const float* __restrict__ p_a,
    const float* __restrict__ p_b,
    float* __restrict__ out,
    int T, int N)
{
#pragma clang fp contract(off)
    const int l     = threadIdx.x;
    const int nbase = blockIdx.x * 64;
    int n = nbase + l;
    if (n >= N) n = N - 1;

    const float V_rest  = *p_V_rest;
    const float V_reset = *p_V_reset;
    const float V_T     = *p_V_T;
    const float V_thres = *p_V_thres;
    const float delta_T = *p_delta_T;
    const float R       = *p_R;
    const float tau     = *p_tau;
    const float tau_w   = *p_tau_w;
    const float a       = *p_a;
    const float b       = *p_b;
    const float dt      = 5e-5f;

    const double dT  = (double)delta_T;
    const double dcv = (double)dt / (double)tau;
    const double dcw = (double)dt / (double)tau_w;
    const double l2e = 1.4426950408889634;

    const float c_exp = (float)(l2e / dT);
    const float c2    = (float)(log2(dT * dcv) - (double)V_T * (l2e / dT));
    const float alpha = (float)(1.0 - dcv);
    const float ncRv  = (float)(-dcv * (double)R);
    const float beta  = (float)(1.0 - dcw);
    const float gamma = (float)((double)a * dcw);
    const float delta = (float)(-(double)a * dcw * (double)V_rest);
    const float cRI   = (float)(dcv * (double)R);
    const float cVr2  = (float)(dcv * (double)V_rest);

    float V = V0[n];
    float w = w0[n];

    float* outVb = out + nbase;
    float* outWb = out + (size_t)T * N + nbase;

#define ADEX_STEP(Ar2_k)                                            \
    {                                                               \
        outVb[l] = V;                                               \
        outWb[l] = w;                                               \
        outVb += N;                                                 \
        outWb += N;                                                 \
        float ex3 = exp2_raw(fmaf(V, c_exp, c2));                   \
        float m1  = fmaf(alpha, V, (Ar2_k));                        \
        float m2  = fmaf(ncRv, w, m1);                              \
        float Vn  = m2 + ex3;                                       \
        float t2  = fmaf(gamma, V, delta);                          \
        float wn  = fmaf(beta, w, t2);                              \
        bool  spike = V > V_thres;                                  \
        float wns = wn + b;                                         \
        Vn = spike ? V_reset : Vn;                                  \
        wn = spike ? wns : wn;                                      \
        V = Vn;                                                     \
        w = wn;                                                     \
    }

    float A[16], B[16];
#pragma unroll
    for (int j = 0; j < 16; ++j) A[j] = fmaf(cRI, I_ext[j], cVr2);

    for (int kb = 0; kb < T; kb += 32) {
#pragma unroll
        for (int j = 0; j < 16; ++j)
            B[j] = fmaf(cRI, I_ext[kb + 16 + j], cVr2);
#pragma unroll
        for (int j = 0; j < 16; ++j) ADEX_STEP(A[j]);
        {
            int pb = kb + 32;
            if (pb > T - 11) pb = T - 11;
#pragma unroll
            for (int j = 0; j < 16; ++j)
                A[j] = fmaf(cRI, I_ext[pb + j], cVr2);
        }
#pragma unroll
        for (int j = 0; j < 16; ++j) ADEX_STEP(B[j]);
    }
#undef ADEX_STEP
}

extern "C" void kernel_launch(void* const* d_in, const int* in_sizes, int n_in,
                              void* d_out, int out_size, void* d_ws, size_t ws_size,
                              hipStream_t stream) {
    const float* I_ext = (const float*)d_in[0];
    const float* V0    = (const float*)d_in[1];
    const float* w0    = (const float*)d_in[2];

    const int N = in_sizes[1];          // 1024 (multiple of 64)
    const int T = out_size / (2 * N);   // 40000 (multiple of 64)

    const size_t ws_need = (size_t)(T + 32) * sizeof(float2);

    if ((N % 64 == 0) && (T % 64 == 0) && d_ws != nullptr && ws_size >= ws_need) {
        adex_prep_kernel<<<(T + 32 + 255) / 256, 256, 0, stream>>>(
            I_ext,
            (const float*)d_in[3],      // V_rest
            (const float*)d_in[8],      // R
            (const float*)d_in[9],      // tau
            (const float*)d_in[10],     // tau_w
            (const float*)d_in[11],     // a
            (float2*)d_ws, T);
        adex_pc_kernel<<<N / 64, 128, 0, stream>>>(
            V0, w0,
            (const float*)d_in[4],      // V_reset
            (const float*)d_in[5],      // V_T
            (const float*)d_in[6],      // V_thres
            (const float*)d_in[7],      // delta_T
            (const float*)d_in[8],      // R
            (const float*)d_in[9],      // tau
            (const float*)d_in[10],     // tau_w
            (const float*)d_in[11],     // a
            (const float*)d_in[12],     // b
            (const float*)d_ws,
            (float*)d_out, T, N);
    } else {
        adex_fallback_kernel<<<(N + 63) / 64, 64, 0, stream>>>(
            I_ext, V0, w0,
            (const float*)d_in[3], (const float*)d_in[4], (const float*)d_in[5],
            (const float*)d_in[6], (const float*)d_in[7], (const float*)d_in[8],
            (const float*)d_in[9], (const float*)d_in[10], (const float*)d_in[11],
            (const float*)d_in[12], (float*)d_out, T, N);
    }
}